// Round 3
// baseline (372.358 us; speedup 1.0000x reference)
//
#include <hip/hip_runtime.h>
#include <hip/hip_bf16.h>
#include <hip/hip_cooperative_groups.h>
#include <math.h>

#define NB   64      // batch
#define NN   307     // n
#define MM   614     // 2n
#define DD   64      // d_in = d_out
#define CAP  64      // max nnz per A-row/col (observed max ~33, +12 sigma to 64)
#define LRA  0.2f    // leaky relu slope
#define WHB  39      // ceil(614/16) Wh groups per batch
#define WHG  (NB * WHB)  // 2496 Wh block-tasks
#define NTASK (NB * NN)  // 19648 wave-tasks for stats/out

__device__ __forceinline__ float wave_sum(float v) {
  #pragma unroll
  for (int m = 32; m >= 1; m >>= 1) v += __shfl_xor(v, m);
  return v;
}
__device__ __forceinline__ float lrelu(float v) { return v > 0.f ? v : LRA * v; }

__global__ __launch_bounds__(256, 4) void k_gat(
    const float* __restrict__ h, const float* __restrict__ ht,
    const float* __restrict__ W, const float* __restrict__ a,
    const float* __restrict__ adj,
    int* __restrict__ arow_cnt, int* __restrict__ arow_idx,
    int* __restrict__ acol_cnt, int* __restrict__ acol_idx,
    float* __restrict__ Wh, float* __restrict__ Wh1, float* __restrict__ Wh2,
    float4* __restrict__ stats, float* __restrict__ out) {
  cooperative_groups::grid_group grid = cooperative_groups::this_grid();
  __shared__ float Wl[DD * DD];
  __shared__ int cnt;
  const int tid  = threadIdx.x;
  const int bid  = blockIdx.x;
  const int nblk = gridDim.x;
  const int lane = tid & 63;
  const int wvu  = __builtin_amdgcn_readfirstlane(tid >> 6);

  // stage W once (used by Wh tasks)
  #pragma unroll
  for (int k = 0; k < 16; k++) Wl[tid + k * 256] = W[tid + k * 256];
  __syncthreads();
  const float a1 = a[lane], a2 = a[64 + lane];

  // ---------------- Phase A: adjacency lists + Wh/Wh1/Wh2 ----------------
  for (int t = bid; t < 2 * NN + WHG; t += nblk) {
    if (t < 2 * NN) {
      if (tid == 0) cnt = 0;
      __syncthreads();
      if (t < NN) {                       // CSR row scan (coalesced)
        for (int j = tid; j < NN; j += 256)
          if (adj[(size_t)t * MM + j] > 0.f)
            arow_idx[t * CAP + atomicAdd(&cnt, 1)] = j;
        __syncthreads();
        if (tid == 0) arow_cnt[t] = cnt;
      } else {                            // CSC col scan
        int c = t - NN;
        for (int i = tid; i < NN; i += 256)
          if (adj[(size_t)i * MM + c] > 0.f)
            acol_idx[c * CAP + atomicAdd(&cnt, 1)] = i;
        __syncthreads();
        if (tid == 0) acol_cnt[c] = cnt;
      }
    } else {                              // Wh GEMV: 16 rows/block, 4/wave
      int g = t - 2 * NN;
      int b = g / WHB;
      int r0 = (g % WHB) * 16 + wvu * 4;
      const float* xp[4];
      bool valid[4];
      #pragma unroll
      for (int j = 0; j < 4; j++) {
        int r = r0 + j;
        valid[j] = (r < MM);
        int rc = valid[j] ? r : 0;
        xp[j] = (rc < NN) ? (ht + ((size_t)b * NN + rc) * DD)
                          : (h  + ((size_t)b * NN + (rc - NN)) * DD);
      }
      float acc0 = 0.f, acc1 = 0.f, acc2 = 0.f, acc3 = 0.f;
      #pragma unroll
      for (int i = 0; i < 64; i++) {
        float w = Wl[i * 64 + lane];
        acc0 = fmaf(xp[0][i], w, acc0);
        acc1 = fmaf(xp[1][i], w, acc1);
        acc2 = fmaf(xp[2][i], w, acc2);
        acc3 = fmaf(xp[3][i], w, acc3);
      }
      float accs[4] = {acc0, acc1, acc2, acc3};
      #pragma unroll
      for (int j = 0; j < 4; j++) {
        float p1 = wave_sum(accs[j] * a1);
        float p2 = wave_sum(accs[j] * a2);
        int r = r0 + j;
        if (valid[j]) {
          Wh[((size_t)(b * MM + r)) * DD + lane] = accs[j];
          if (lane == 0) { Wh1[b * MM + r] = p1; Wh2[b * MM + r] = p2; }
        }
      }
    }
  }

  __threadfence();
  grid.sync();

  // ---------------- Phase B: column-pair softmax denominators ----------------
  const int gw = bid * 4 + (tid >> 6);
  const int nwv = nblk * 4;
  for (int t = gw; t < NTASK; t += nwv) {
    int b = t / NN, j = t - b * NN;
    const float* wh1 = Wh1 + (size_t)b * MM;
    float wh2j  = Wh2[(size_t)b * MM + j];
    float wh2nj = Wh2[(size_t)b * MM + NN + j];
    int ccnt = acol_cnt[j];
    bool v = lane < ccnt;
    float s0 = 0.f, s1 = 0.f;
    if (v) {
      int i = acol_idx[j * CAP + lane];
      s0 = __expf(lrelu(wh1[i] + wh2j));
      s1 = __expf(lrelu(wh1[NN + i] + wh2nj));
    }
    s0 = wave_sum(s0);
    s1 = wave_sum(s1);
    s1 += __expf(lrelu(wh1[j] + wh2nj));   // identity entry of column n+j
    if (lane == 0) stats[t] = make_float4(wh2j, wh2nj, 1.f / s0, 1.f / s1);
  }

  __threadfence();
  grid.sync();

  // ---------------- Phase C: row-pair output (sparse att @ Wh) ----------------
  for (int t = gw; t < NTASK; t += nwv) {
    int b = t / NN, i = t - b * NN;
    const float* whB = Wh + (size_t)b * MM * DD;
    float wh1a = Wh1[(size_t)b * MM + i];
    float wh1b = Wh1[(size_t)b * MM + NN + i];
    int rcnt = arow_cnt[i];
    bool v = lane < rcnt;
    int j = 0;
    float w0 = 0.f, w1 = 0.f;
    if (v) {
      j = arow_idx[i * CAP + lane];
      float4 st = stats[(size_t)b * NN + j];
      w0 = __expf(lrelu(wh1a + st.x)) * st.z;
      w1 = __expf(lrelu(wh1b + st.y)) * st.w;
    }
    float acc0a = 0.f, acc0b = 0.f, acc1a = 0.f, acc1b = 0.f;
    for (int k = 0; k + 1 < rcnt; k += 2) {
      int   jka = __shfl(j, k),      jkb = __shfl(j, k + 1);
      float w0a = __shfl(w0, k),     w0b = __shfl(w0, k + 1);
      float w1a = __shfl(w1, k),     w1b = __shfl(w1, k + 1);
      acc0a = fmaf(w0a, whB[(size_t)jka * DD + lane], acc0a);
      acc1a = fmaf(w1a, whB[(size_t)(NN + jka) * DD + lane], acc1a);
      acc0b = fmaf(w0b, whB[(size_t)jkb * DD + lane], acc0b);
      acc1b = fmaf(w1b, whB[(size_t)(NN + jkb) * DD + lane], acc1b);
    }
    if (rcnt & 1) {
      int k = rcnt - 1;
      int   jka = __shfl(j, k);
      float w0a = __shfl(w0, k), w1a = __shfl(w1, k);
      acc0a = fmaf(w0a, whB[(size_t)jka * DD + lane], acc0a);
      acc1a = fmaf(w1a, whB[(size_t)(NN + jka) * DD + lane], acc1a);
    }
    // identity entry: row i attends column n+i
    float4 sti = stats[(size_t)b * NN + i];
    acc0a = fmaf(__expf(lrelu(wh1a + sti.y)) * sti.w,
                 whB[(size_t)(NN + i) * DD + lane], acc0a);
    float acc0 = acc0a + acc0b, acc1 = acc1a + acc1b;
    float r0 = acc0 > 0.f ? acc0 : expm1f(acc0);   // ELU
    float r1 = acc1 > 0.f ? acc1 : expm1f(acc1);
    out[((size_t)(b * NN + i)) * 128 + lane]      = r0;
    out[((size_t)(b * NN + i)) * 128 + 64 + lane] = r1;
  }
}

extern "C" void kernel_launch(void* const* d_in, const int* in_sizes, int n_in,
                              void* d_out, int out_size, void* d_ws, size_t ws_size,
                              hipStream_t stream) {
  const float* h   = (const float*)d_in[0];
  const float* ht  = (const float*)d_in[1];
  const float* W   = (const float*)d_in[2];
  const float* a   = (const float*)d_in[3];
  const float* adj = (const float*)d_in[4];
  float* out = (float*)d_out;

  char* ws = (char*)d_ws;
  size_t off = 0;
  auto alloc = [&](size_t bytes) -> void* {
    void* p = ws + off;
    off = (off + bytes + 255) & ~(size_t)255;
    return p;
  };
  float*  Wh       = (float*)alloc((size_t)NB * MM * DD * 4);
  float4* stats    = (float4*)alloc((size_t)NB * NN * 16);
  float*  Wh1      = (float*)alloc((size_t)NB * MM * 4);
  float*  Wh2      = (float*)alloc((size_t)NB * MM * 4);
  int*    arow_cnt = (int*)alloc(NN * 4);
  int*    acol_cnt = (int*)alloc(NN * 4);
  int*    arow_idx = (int*)alloc((size_t)NN * CAP * 4);
  int*    acol_idx = (int*)alloc((size_t)NN * CAP * 4);

  // grid: co-resident capacity (host-side queries only; runs during capture, not replay)
  int dev = 0;
  hipGetDevice(&dev);
  hipDeviceProp_t props;
  hipGetDeviceProperties(&props, dev);
  int maxb = 0;
  hipOccupancyMaxActiveBlocksPerMultiprocessor(&maxb, k_gat, 256, 0);
  if (maxb < 1) maxb = 1;
  int nblk = maxb * props.multiProcessorCount;
  if (nblk > 1024) nblk = 1024;

  void* args[] = {(void*)&h, (void*)&ht, (void*)&W, (void*)&a, (void*)&adj,
                  (void*)&arow_cnt, (void*)&arow_idx,
                  (void*)&acol_cnt, (void*)&acol_idx,
                  (void*)&Wh, (void*)&Wh1, (void*)&Wh2,
                  (void*)&stats, (void*)&out};
  hipLaunchCooperativeKernel((void*)k_gat, dim3(nblk), dim3(256), args, 0, stream);
}

// Round 4
// 138.925 us; speedup vs baseline: 2.6803x; 2.6803x over previous
//
#include <hip/hip_runtime.h>
#include <hip/hip_bf16.h>
#include <math.h>

#define NB   64      // batch
#define NN   307     // n
#define MM   614     // 2n
#define DD   64      // d_in = d_out
#define CAP  64      // max nnz per A-row/col (observed max ~33; 64 = +12 sigma)
#define LRA  0.2f    // leaky relu slope
#define WHB  39      // ceil(614/16) Wh groups per batch
#define NTASK (NB * NN)  // 19648 wave-tasks

__device__ __forceinline__ float wave_sum(float v) {
  #pragma unroll
  for (int m = 32; m >= 1; m >>= 1) v += __shfl_xor(v, m);
  return v;
}
__device__ __forceinline__ float lrelu(float v) { return v > 0.f ? v : LRA * v; }

// ---------------- K1: fused {A-row build | A-col build | Wh GEMV} -----------
__global__ __launch_bounds__(256) void k_prep(const float* __restrict__ h,
    const float* __restrict__ ht, const float* __restrict__ W,
    const float* __restrict__ a, const float* __restrict__ adj,
    int* __restrict__ arow_cnt, int* __restrict__ arow_idx,
    int* __restrict__ acol_cnt, int* __restrict__ acol_idx,
    float* __restrict__ Wh, float* __restrict__ Wh1, float* __restrict__ Wh2) {
  int tid = threadIdx.x;
  int bid = blockIdx.x;

  if (bid < 2 * NN) {                       // ---- adjacency build roles ----
    __shared__ int cnt;
    if (tid == 0) cnt = 0;
    __syncthreads();
    if (bid < NN) {                         // CSR row scan (coalesced)
      int r = bid;
      for (int j = tid; j < NN; j += 256)
        if (adj[(size_t)r * MM + j] > 0.f)
          arow_idx[r * CAP + atomicAdd(&cnt, 1)] = j;
      __syncthreads();
      if (tid == 0) arow_cnt[r] = cnt;
    } else {                                // CSC col scan
      int c = bid - NN;
      for (int i = tid; i < NN; i += 256)
        if (adj[(size_t)i * MM + c] > 0.f)
          acol_idx[c * CAP + atomicAdd(&cnt, 1)] = i;
      __syncthreads();
      if (tid == 0) acol_cnt[c] = cnt;
    }
    return;
  }

  // ---- Wh GEMV role: 4 waves/block, 4 rows/wave, x staged transposed in LDS
  __shared__ float Wl[DD * DD];             // W[i][o], row-major, 16 KB
  __shared__ float xst[4][DD][4];           // [wave][elem i][row j], 4 KB
  #pragma unroll
  for (int k = 0; k < 16; k++) Wl[tid + k * 256] = W[tid + k * 256];

  int lane = tid & 63;
  int wv   = __builtin_amdgcn_readfirstlane(tid >> 6);
  int blk  = bid - 2 * NN;
  int b    = blk / WHB;
  int r0   = (blk % WHB) * 16 + wv * 4;

  // row pointers (clamped so loads stay in-bounds)
  const float* xp[4];
  bool valid[4];
  #pragma unroll
  for (int j = 0; j < 4; j++) {
    int r = r0 + j;
    valid[j] = (r < MM);
    int rc = valid[j] ? r : 0;
    xp[j] = (rc < NN) ? (ht + ((size_t)b * NN + rc) * DD)
                      : (h  + ((size_t)b * NN + (rc - NN)) * DD);
  }
  // transposed stage: lane l handles row (l&3), elems t*16 + (l>>2)
  int jr = lane & 3, el = lane >> 2;
  #pragma unroll
  for (int t = 0; t < 4; t++) {
    float v = xp[jr][t * 16 + el];
    xst[wv][t * 16 + el][jr] = v;           // consecutive addr across lane -> conflict-free
  }
  __syncthreads();                          // Wl cross-wave; xst same-wave

  float a1 = a[lane], a2 = a[64 + lane];
  float acc0 = 0.f, acc1 = 0.f, acc2 = 0.f, acc3 = 0.f;
  #pragma unroll
  for (int i = 0; i < 64; i++) {
    float4 xv = *(const float4*)&xst[wv][i][0];   // ds_read_b128 broadcast
    float w = Wl[i * 64 + lane];                  // conflict-free b32
    acc0 = fmaf(xv.x, w, acc0);
    acc1 = fmaf(xv.y, w, acc1);
    acc2 = fmaf(xv.z, w, acc2);
    acc3 = fmaf(xv.w, w, acc3);
  }

  float accs[4] = {acc0, acc1, acc2, acc3};
  #pragma unroll
  for (int j = 0; j < 4; j++) {
    float p1 = wave_sum(accs[j] * a1);
    float p2 = wave_sum(accs[j] * a2);
    int r = r0 + j;
    if (valid[j]) {
      Wh[((size_t)(b * MM + r)) * DD + lane] = accs[j];
      if (lane == 0) { Wh1[b * MM + r] = p1; Wh2[b * MM + r] = p2; }
    }
  }
}

// ---------------- K2: column-pair softmax denominators (single pass) --------
__global__ __launch_bounds__(256) void k_stats(const float* __restrict__ Wh1,
    const float* __restrict__ Wh2, const int* __restrict__ acol_cnt,
    const int* __restrict__ acol_idx, float4* __restrict__ stats) {
  int lane = threadIdx.x & 63;
  int task = blockIdx.x * 4 + (threadIdx.x >> 6);
  int b = task / NN, j = task - b * NN;
  const float* wh1 = Wh1 + (size_t)b * MM;
  float wh2j  = Wh2[(size_t)b * MM + j];
  float wh2nj = Wh2[(size_t)b * MM + NN + j];
  int cnt = acol_cnt[j];
  float s0 = 0.f, s1 = 0.f;
  if (lane < cnt) {
    int i = acol_idx[j * CAP + lane];
    s0 = __expf(lrelu(wh1[i] + wh2j));
    s1 = __expf(lrelu(wh1[NN + i] + wh2nj));
  }
  s0 = wave_sum(s0);
  s1 = wave_sum(s1);
  s1 += __expf(lrelu(wh1[j] + wh2nj));     // identity entry of column n+j
  if (lane == 0) stats[task] = make_float4(wh2j, wh2nj, 1.f / s0, 1.f / s1);
}

// ---------------- K3: row-pair output (sparse att @ Wh), ELU, store ---------
__global__ __launch_bounds__(256) void k_out(const float* __restrict__ Wh,
    const float* __restrict__ Wh1, const float4* __restrict__ stats,
    const int* __restrict__ arow_cnt, const int* __restrict__ arow_idx,
    float* __restrict__ out) {
  int lane = threadIdx.x & 63;
  int bid = blockIdx.x;
  int sb = (bid & 7) * 614 + (bid >> 3);   // XCD swizzle: 4912 = 8*614
  int task = sb * 4 + (threadIdx.x >> 6);
  int b = task / NN, i = task - b * NN;
  const float* whB = Wh + (size_t)b * MM * DD;
  float wh1a = Wh1[(size_t)b * MM + i];
  float wh1b = Wh1[(size_t)b * MM + NN + i];
  int rcnt = arow_cnt[i];
  int j = 0;
  float w0 = 0.f, w1 = 0.f;
  if (lane < rcnt) {
    j = arow_idx[i * CAP + lane];
    float4 st = stats[(size_t)b * NN + j];
    w0 = __expf(lrelu(wh1a + st.x)) * st.z;
    w1 = __expf(lrelu(wh1b + st.y)) * st.w;
  }
  float acc0a = 0.f, acc0b = 0.f, acc1a = 0.f, acc1b = 0.f;
  for (int k = 0; k + 1 < rcnt; k += 2) {
    int   jka = __shfl(j, k),   jkb = __shfl(j, k + 1);
    float w0a = __shfl(w0, k),  w0b = __shfl(w0, k + 1);
    float w1a = __shfl(w1, k),  w1b = __shfl(w1, k + 1);
    const float* pa = whB + (size_t)jka * DD + lane;
    const float* pb = whB + (size_t)jkb * DD + lane;
    acc0a = fmaf(w0a, pa[0], acc0a);
    acc1a = fmaf(w1a, pa[NN * DD], acc1a);
    acc0b = fmaf(w0b, pb[0], acc0b);
    acc1b = fmaf(w1b, pb[NN * DD], acc1b);
  }
  if (rcnt & 1) {
    int k = rcnt - 1;
    int   jka = __shfl(j, k);
    float w0a = __shfl(w0, k), w1a = __shfl(w1, k);
    const float* pa = whB + (size_t)jka * DD + lane;
    acc0a = fmaf(w0a, pa[0], acc0a);
    acc1a = fmaf(w1a, pa[NN * DD], acc1a);
  }
  // identity entry: row i attends column n+i
  float4 sti = stats[(size_t)b * NN + i];
  acc0a = fmaf(__expf(lrelu(wh1a + sti.y)) * sti.w,
               whB[(size_t)(NN + i) * DD + lane], acc0a);
  float acc0 = acc0a + acc0b, acc1 = acc1a + acc1b;
  float r0 = acc0 > 0.f ? acc0 : expm1f(acc0);   // ELU
  float r1 = acc1 > 0.f ? acc1 : expm1f(acc1);
  out[((size_t)(b * NN + i)) * 128 + lane]      = r0;
  out[((size_t)(b * NN + i)) * 128 + 64 + lane] = r1;
}

extern "C" void kernel_launch(void* const* d_in, const int* in_sizes, int n_in,
                              void* d_out, int out_size, void* d_ws, size_t ws_size,
                              hipStream_t stream) {
  const float* h   = (const float*)d_in[0];
  const float* ht  = (const float*)d_in[1];
  const float* W   = (const float*)d_in[2];
  const float* a   = (const float*)d_in[3];
  const float* adj = (const float*)d_in[4];
  float* out = (float*)d_out;

  char* ws = (char*)d_ws;
  size_t off = 0;
  auto alloc = [&](size_t bytes) -> void* {
    void* p = ws + off;
    off = (off + bytes + 255) & ~(size_t)255;
    return p;
  };
  float*  Wh       = (float*)alloc((size_t)NB * MM * DD * 4);
  float4* stats    = (float4*)alloc((size_t)NB * NN * 16);
  float*  Wh1      = (float*)alloc((size_t)NB * MM * 4);
  float*  Wh2      = (float*)alloc((size_t)NB * MM * 4);
  int*    arow_cnt = (int*)alloc(NN * 4);
  int*    acol_cnt = (int*)alloc(NN * 4);
  int*    arow_idx = (int*)alloc((size_t)NN * CAP * 4);
  int*    acol_idx = (int*)alloc((size_t)NN * CAP * 4);

  k_prep<<<2 * NN + NB * WHB, 256, 0, stream>>>(h, ht, W, a, adj,
      arow_cnt, arow_idx, acol_cnt, acol_idx, Wh, Wh1, Wh2);
  k_stats<<<NTASK / 4, 256, 0, stream>>>(Wh1, Wh2, acol_cnt, acol_idx, stats);
  k_out<<<NTASK / 4, 256, 0, stream>>>(Wh, Wh1, stats, arow_cnt, arow_idx, out);
}